// Round 11
// baseline (145.475 us; speedup 1.0000x reference)
//
#include <hip/hip_runtime.h>
#include <hip/hip_bf16.h>

// MambaBlock: H=256, S=16, B=2, N=8192. fp32 I/O.
// No decay (A_log unused) => pure prefix-sum SSM, chunk-parallel.
// Round 11: 512-thread blocks for k1/kS/k56 (16 waves/CU at same LDS),
// phases split across 8 waves; k56 Hst prefetch hoisted above first barrier.

#define HD 256
#define SD 16
#define NSEQ 8192
#define NBATCH 2
#define BN (NBATCH * NSEQ)      // 16384 rows
#define CHUNK 32
#define NCHUNK (NSEQ / CHUNK)   // 256
#define NGRP 16
#define GSZ (NCHUNK / NGRP)     // 16
#define LN_EPS 1e-5f
#define UST 40                  // bf16 row stride for Ut/Hst/Ctl
#define PST 257                 // f32 row stride for pt

#define NIW (2 * HD * HD)       // 131,072 in_w
#define NXP (48 * HD)           // 12,288  xp_w padded (src 33*256=8448)
#define NOW (HD * HD)           // 65,536  out_w

typedef __hip_bfloat16 bf16;
typedef __attribute__((ext_vector_type(8))) short bf16x8;
typedef __attribute__((ext_vector_type(4))) short short4v;
typedef __attribute__((ext_vector_type(4))) float f32x4;
typedef __attribute__((ext_vector_type(4))) unsigned int uint4v;

__device__ __forceinline__ float b2f(bf16 v) { return __bfloat162float(v); }
__device__ __forceinline__ short f2bs(float f) {
  union { bf16 b; short s; } u;
  u.b = __float2bfloat16(f);
  return u.s;
}
__device__ __forceinline__ unsigned int pack2(float a, float b) {
  return (unsigned int)(unsigned short)f2bs(a) |
         ((unsigned int)(unsigned short)f2bs(b) << 16);
}
__device__ __forceinline__ bf16x8 cvt_frag(const float* p) {
  bf16x8 r;
#pragma unroll
  for (int j = 0; j < 8; ++j) r[j] = f2bs(p[j]);
  return r;
}
__device__ __forceinline__ float softplus_f(float a) {
  return (a > 20.f) ? a : __logf(1.f + __expf(a));
}

// ---------------------------------------------------------------------------
// K0: weight conversions only.
// ---------------------------------------------------------------------------
__global__ __launch_bounds__(256) void k0_weights(
    const float* __restrict__ in_w, const float* __restrict__ xp_w,
    const float* __restrict__ out_w, bf16* __restrict__ wbin,
    bf16* __restrict__ wbxp, bf16* __restrict__ wbout)
{
  const int base = (blockIdx.x * 256 + threadIdx.x) * 4;
  if (base < NIW) {
    f32x4 v = *(const f32x4*)(in_w + base);
    *(short4v*)((short*)wbin + base) =
        short4v{f2bs(v[0]), f2bs(v[1]), f2bs(v[2]), f2bs(v[3])};
  } else if (base < NIW + NXP) {
    const int off = base - NIW;
    short4v s;
    if (off < 33 * HD) {
      f32x4 v = *(const f32x4*)(xp_w + off);
      s = short4v{f2bs(v[0]), f2bs(v[1]), f2bs(v[2]), f2bs(v[3])};
    } else {
      s = short4v{0, 0, 0, 0};
    }
    *(short4v*)((short*)wbxp + off) = s;
  } else if (base < NIW + NXP + NOW) {
    const int off = base - NIW - NXP;
    f32x4 v = *(const f32x4*)(out_w + off);
    *(short4v*)((short*)wbout + off) =
        short4v{f2bs(v[0]), f2bs(v[1]), f2bs(v[2]), f2bs(v[3])};
  }
}

// ---------------------------------------------------------------------------
// K1: tiled GEMM [x_inner|z] = x @ in_w^T + in_b (bf16 out). 512 thr/8 waves,
// wave tile 32x64. A staged fp32->bf16 in LDS (aliased with epilogue Ct).
// rt = bid&127: 4 col-blocks of a row-tile share one XCD's L2 for A.
// ---------------------------------------------------------------------------
__global__ __launch_bounds__(512) void k1_gemm(
    const float* __restrict__ x, const bf16* __restrict__ wbin,
    const float* __restrict__ in_b, bf16* __restrict__ xib,
    bf16* __restrict__ zb)
{
  __shared__ __align__(16) char smem[128 * 264 * 2];   // 67,584 B
  bf16* At = (bf16*)smem;        // [128][264] bf16 A-tile
  float* Ct = (float*)smem;      // [128][132] f32, aliased after GEMM

  const int tid = threadIdx.x;
  const int rt = blockIdx.x & 127, ct = blockIdx.x >> 7;
  const int R0 = rt * 128, C0 = ct * 128;
  const int wave = tid >> 6, lane = tid & 63, q = lane >> 4, l16 = lane & 15;

  // stage A: 128 rows x 32 groups = 4096 groups of 8, 8 iters
#pragma unroll
  for (int it = 0; it < 8; ++it) {
    const int f = tid + it * 512;
    const int row = f >> 5, g = f & 31;
    bf16x8 v = cvt_frag(x + (size_t)(R0 + row) * HD + g * 8);
    *(bf16x8*)(At + row * 264 + g * 8) = v;
  }
  __syncthreads();

  // GEMM: wave = 32 rows x 64 cols
  const int rowQ = (wave & 3) * 32;
  const int colH = (wave >> 2) * 64;
  f32x4 acc[2][4] = {};
  const bf16* bp = wbin + (size_t)(C0 + colH + l16) * HD + q * 8;
#pragma unroll
  for (int k = 0; k < HD; k += 32) {
    bf16x8 a[2], b[4];
#pragma unroll
    for (int i = 0; i < 2; ++i)
      a[i] = *(const bf16x8*)(At + (rowQ + i * 16 + l16) * 264 + k + q * 8);
#pragma unroll
    for (int j = 0; j < 4; ++j)
      b[j] = *(const bf16x8*)(bp + (size_t)j * 16 * HD + k);
#pragma unroll
    for (int i = 0; i < 2; ++i)
#pragma unroll
      for (int j = 0; j < 4; ++j)
        acc[i][j] = __builtin_amdgcn_mfma_f32_16x16x32_bf16(a[i], b[j], acc[i][j], 0, 0, 0);
  }
  __syncthreads();   // At reads complete before Ct overwrite

#pragma unroll
  for (int j = 0; j < 4; ++j) {
    const int col = colH + j * 16 + l16;
    const float bias = in_b[C0 + col];
#pragma unroll
    for (int i = 0; i < 2; ++i)
#pragma unroll
      for (int r = 0; r < 4; ++r)
        Ct[(rowQ + i * 16 + q * 4 + r) * 132 + col] = acc[i][j][r] + bias;
  }
  __syncthreads();

  bf16* dst = (C0 < HD) ? xib : zb;
  const int Cd = (C0 < HD) ? C0 : (C0 - HD);
#pragma unroll
  for (int it = 0; it < 4; ++it) {
    const int f = tid + it * 512;           // 128 rows x 16 groups of 8
    const int row = f >> 4, g = f & 15;
    bf16x8 v = cvt_frag(Ct + row * 132 + g * 8);
    *(bf16x8*)(dst + (size_t)(R0 + row) * HD + Cd + g * 8) = v;
  }
}

// ---------------------------------------------------------------------------
// KS: per 32-row chunk (512 thr): xp-GEMM -> dbc; u -> Ut[h][n] (split over
// (h, n-half)); Mc = B^T @ U via MFMA over 8 waves x 2 col-tiles.
// ---------------------------------------------------------------------------
__global__ __launch_bounds__(512) void kS_xp_sum(
    const bf16* __restrict__ xib, const bf16* __restrict__ wbxp,
    const float* __restrict__ xp_b, const float* __restrict__ dt_w,
    const float* __restrict__ dt_b, float* __restrict__ dbc,
    float* __restrict__ Mc)
{
  __shared__ __align__(16) bf16 xt[32 * 264];    // 16.9 KB
  __shared__ __align__(16) bf16 wp[48 * 264];    // 25.3 KB
  __shared__ __align__(16) float sdbc[32][33];   // 4.2 KB
  __shared__ __align__(16) bf16 sBt[16 * UST];   // 1.25 KB
  __shared__ __align__(16) bf16 Ut[256 * UST];   // 20 KB
  const int tid = threadIdx.x;
  const int wave = tid >> 6, lane = tid & 63, q = lane >> 4, l16 = lane & 15;
  const int cix = blockIdx.x;
  const int R0 = cix * CHUNK;

#pragma unroll
  for (int it = 0; it < 2; ++it) {
    const int f = tid + it * 512, row = f >> 5, g = f & 31;
    *(bf16x8*)(xt + row * 264 + g * 8) =
        *(const bf16x8*)(xib + (size_t)(R0 + row) * HD + g * 8);
  }
#pragma unroll
  for (int it = 0; it < 3; ++it) {
    const int f = tid + it * 512, row = f >> 5, g = f & 31;
    *(bf16x8*)(wp + row * 264 + g * 8) =
        *(const bf16x8*)(wbxp + (size_t)row * HD + g * 8);
  }
  __syncthreads();

  if (wave < 2) {
    f32x4 pacc[3] = {};
#pragma unroll
    for (int k = 0; k < HD; k += 32) {
      bf16x8 af = *(const bf16x8*)(xt + (wave * 16 + l16) * 264 + k + q * 8);
#pragma unroll
      for (int t = 0; t < 3; ++t) {
        bf16x8 bfr = *(const bf16x8*)(wp + (t * 16 + l16) * 264 + k + q * 8);
        pacc[t] = __builtin_amdgcn_mfma_f32_16x16x32_bf16(af, bfr, pacc[t], 0, 0, 0);
      }
    }
#pragma unroll
    for (int t = 0; t < 3; ++t) {
      const int col = t * 16 + l16;
      if (col < 33) {
        const float bias = xp_b[col];
#pragma unroll
        for (int r = 0; r < 4; ++r) {
          const int row = wave * 16 + q * 4 + r;
          const float v = pacc[t][r] + bias;
          sdbc[row][col] = v;
          if (col >= 1 && col < 17)
            *((short*)sBt + (col - 1) * UST + row) = f2bs(v);
        }
      }
    }
  }
  __syncthreads();

  // dbc flat copy out
  {
    const float* sflat = &sdbc[0][0];
    for (int idx = tid; idx < CHUNK * 33; idx += 512)
      dbc[(size_t)R0 * 33 + idx] = sflat[idx];
  }
  // u -> Ut[h][n], split (h, n-half)
  {
    const int h = tid & 255;
    const int sh = tid >> 8;            // n-half
    const float dtw = dt_w[h], dtb = dt_b[h];
    unsigned int up[8];
#pragma unroll
    for (int n2 = 0; n2 < 8; ++n2) {
      const int n = sh * 16 + 2 * n2;
      const float xv0 = b2f(xt[n * 264 + h]);
      const float xv1 = b2f(xt[(n + 1) * 264 + h]);
      const float u0 = xv0 * softplus_f(sdbc[n][0] * dtw + dtb);
      const float u1 = xv1 * softplus_f(sdbc[n + 1][0] * dtw + dtb);
      up[n2] = pack2(u0, u1);
    }
    uint4v* dst = (uint4v*)(Ut + h * UST + sh * 16);
    dst[0] = uint4v{up[0], up[1], up[2], up[3]};
    dst[1] = uint4v{up[4], up[5], up[6], up[7]};
  }
  __syncthreads();

  // Mc = B^T @ U : 8 waves x 2 col-tiles
  {
    bf16x8 af = *(const bf16x8*)(sBt + l16 * UST + q * 8);
    f32x4 macc[2] = {};
#pragma unroll
    for (int c2 = 0; c2 < 2; ++c2) {
      const int ct = wave * 2 + c2;
      bf16x8 bu = *(const bf16x8*)(Ut + (ct * 16 + l16) * UST + q * 8);
      macc[c2] = __builtin_amdgcn_mfma_f32_16x16x32_bf16(af, bu, macc[c2], 0, 0, 0);
    }
    float* mbase = Mc + (size_t)cix * 4096;
#pragma unroll
    for (int c2 = 0; c2 < 2; ++c2) {
      const int h = (wave * 2 + c2) * 16 + l16;
#pragma unroll
      for (int r = 0; r < 4; ++r)
        mbase[(q * 4 + r) * HD + h] = macc[c2][r];   // [s][h]
    }
  }
}

// ---------------------------------------------------------------------------
// K4a: exclusive prefix of Mc within each group of GSZ chunks; totals -> Gs.
// ---------------------------------------------------------------------------
__global__ __launch_bounds__(256) void k4a_prefix_local(
    float* __restrict__ Mc, float* __restrict__ Gs)
{
  const int tid = blockIdx.x * 256 + threadIdx.x;   // 131072
  const int b = tid >> 16;
  const int g = (tid >> 12) & (NGRP - 1);
  const int hs = tid & 4095;
  float run = 0.f;
#pragma unroll
  for (int i = 0; i < GSZ; ++i) {
    const size_t idx = ((size_t)(b * NCHUNK + g * GSZ + i)) * 4096 + hs;
    const float v = Mc[idx];
    Mc[idx] = run;
    run += v;
  }
  Gs[((size_t)(b * NGRP + g)) * 4096 + hs] = run;
}

// ---------------------------------------------------------------------------
// K4b: exclusive prefix over the NGRP group totals (in-place).
// ---------------------------------------------------------------------------
__global__ __launch_bounds__(256) void k4b_prefix_groups(float* __restrict__ Gs)
{
  const int tid = blockIdx.x * 256 + threadIdx.x;   // 8192
  const int b = tid >> 12;
  const int hs = tid & 4095;
  float run = 0.f;
#pragma unroll
  for (int g = 0; g < NGRP; ++g) {
    const size_t idx = ((size_t)(b * NGRP + g)) * 4096 + hs;
    const float v = Gs[idx];
    Gs[idx] = run;
    run += v;
  }
}

// ---------------------------------------------------------------------------
// K56 (512 thr / 8 waves): Hst prefetch hoisted; T/Ctl/u built 512-wide;
// y = T@U + C@Hseed (8 waves x 2 col-tiles); gate in regs -> yb bf16;
// out-GEMM 32 cols/wave; residual + LN (4 rows/wave).
// ---------------------------------------------------------------------------
__global__ __launch_bounds__(512) void k56_scan_out_ln(
    const bf16* __restrict__ xib, const bf16* __restrict__ zb,
    const float* __restrict__ dbc, const float* __restrict__ dt_w,
    const float* __restrict__ dt_b, const float* __restrict__ Dv,
    const float* __restrict__ Mc, const float* __restrict__ Gs,
    const bf16* __restrict__ wbout, const float* __restrict__ out_b,
    const float* __restrict__ x, const float* __restrict__ ln_g,
    const float* __restrict__ ln_b, float* __restrict__ out)
{
  __shared__ __align__(16) char un[53376];
  bf16* Ut  = (bf16*)un;                 // [256][UST]  20,480 B
  bf16* Hst = (bf16*)(un + 20480);       // [256][UST]  20,480 B
  bf16* Ctl = (bf16*)(un + 40960);       // [32][UST]    2,560 B
  bf16* Tt  = (bf16*)(un + 43520);       // [32][32]     2,048 B
  bf16* yb  = (bf16*)un;                 // phase3: [32][264] 16,896 B
  float* pt = (float*)(un + 20480);      // phase4: [32][PST] 32,896 B
  __shared__ float sdbc[32][33];

  const int tid = threadIdx.x;
  const int wave = tid >> 6, lane = tid & 63, q = lane >> 4, l16 = lane & 15;
  const int cix = blockIdx.x;
  const int R0 = cix * CHUNK;
  const int b = cix >> 8;
  const int cchunk = cix & 255;

  // ---- Hst prefetch (independent of sdbc -> overlaps its load) ----
  {
    const int h = tid & 255;
    const int sh = tid >> 8;
    const float* mp = Mc + (size_t)cix * 4096 + sh * 8 * HD + h;
    const float* gp = Gs + ((size_t)(b * NGRP + cchunk / GSZ)) * 4096 + sh * 8 * HD + h;
    unsigned int hp[4];
#pragma unroll
    for (int s2 = 0; s2 < 4; ++s2) {
      const int s = 2 * s2;
      hp[s2] = pack2(mp[s * HD] + gp[s * HD], mp[(s + 1) * HD] + gp[(s + 1) * HD]);
    }
    uint4v* hd = (uint4v*)(Hst + h * UST);
    hd[sh] = uint4v{hp[0], hp[1], hp[2], hp[3]};
    hd[2 + sh] = uint4v{0, 0, 0, 0};
  }
  // ---- sdbc load (flat coalesced) ----
  {
    float* sflat = &sdbc[0][0];
    for (int idx = tid; idx < CHUNK * 33; idx += 512)
      sflat[idx] = dbc[(size_t)R0 * 33 + idx];
  }
  __syncthreads();

  // ---- T = (C @ B^T) masked (m <= n): thread = (n, m-pair) ----
  {
    const int n = tid >> 4;
    const int m0 = (tid & 15) * 2;
    float cn[SD];
#pragma unroll
    for (int s = 0; s < SD; ++s) cn[s] = sdbc[n][17 + s];
    float t0 = 0.f, t1 = 0.f;
#pragma unroll
    for (int s = 0; s < SD; ++s) {
      t0 += cn[s] * sdbc[m0][1 + s];
      t1 += cn[s] * sdbc[m0 + 1][1 + s];
    }
    *(unsigned int*)((short*)Tt + n * 32 + m0) =
        pack2((m0 <= n) ? t0 : 0.f, (m0 + 1 <= n) ? t1 : 0.f);
  }
  // ---- Ctl[n][k] = C (k<16) else 0: thread = (n, k-pair) ----
  {
    const int n = tid >> 4, k0 = (tid & 15) * 2;
    const float v0 = (k0 < SD) ? sdbc[n][17 + k0] : 0.f;
    const float v1 = (k0 + 1 < SD) ? sdbc[n][17 + k0 + 1] : 0.f;
    *(unsigned int*)((short*)Ctl + n * UST + k0) = pack2(v0, v1);
  }
  // ---- u -> Ut[h][n], split (h, n-half) ----
  {
    const int h = tid & 255;
    const int sh = tid >> 8;
    const float dtw = dt_w[h], dtb = dt_b[h];
    unsigned int up[8];
#pragma unroll
    for (int n2 = 0; n2 < 8; ++n2) {
      const int n = sh * 16 + 2 * n2;
      const float xv0 = b2f(xib[(size_t)(R0 + n) * HD + h]);
      const float xv1 = b2f(xib[(size_t)(R0 + n + 1) * HD + h]);
      const float u0 = xv0 * softplus_f(sdbc[n][0] * dtw + dtb);
      const float u1 = xv1 * softplus_f(sdbc[n + 1][0] * dtw + dtb);
      up[n2] = pack2(u0, u1);
    }
    uint4v* dst = (uint4v*)(Ut + h * UST + sh * 16);
    dst[0] = uint4v{up[0], up[1], up[2], up[3]};
    dst[1] = uint4v{up[4], up[5], up[6], up[7]};
  }
  __syncthreads();

  // ---- y MFMAs: 8 waves x 2 col-tiles, 2 row-tiles ----
  f32x4 acc[2][2] = {};
  {
    bf16x8 aT0 = *(const bf16x8*)(Tt + l16 * 32 + q * 8);
    bf16x8 aT1 = *(const bf16x8*)(Tt + (16 + l16) * 32 + q * 8);
    bf16x8 aC0 = *(const bf16x8*)(Ctl + l16 * UST + q * 8);
    bf16x8 aC1 = *(const bf16x8*)(Ctl + (16 + l16) * UST + q * 8);
#pragma unroll
    for (int c2 = 0; c2 < 2; ++c2) {
      const int ct = wave * 2 + c2;
      bf16x8 bu = *(const bf16x8*)(Ut + (ct * 16 + l16) * UST + q * 8);
      bf16x8 bh = *(const bf16x8*)(Hst + (ct * 16 + l16) * UST + q * 8);
      acc[0][c2] = __builtin_amdgcn_mfma_f32_16x16x32_bf16(aT0, bu, acc[0][c2], 0, 0, 0);
      acc[0][c2] = __builtin_amdgcn_mfma_f32_16x16x32_bf16(aC0, bh, acc[0][c2], 0, 0, 0);
      acc[1][c2] = __builtin_amdgcn_mfma_f32_16x16x32_bf16(aT1, bu, acc[1][c2], 0, 0, 0);
      acc[1][c2] = __builtin_amdgcn_mfma_f32_16x16x32_bf16(aC1, bh, acc[1][c2], 0, 0, 0);
    }
  }
  __syncthreads();   // operand tiles dead; union becomes yb/pt

  // ---- gate in registers: y = (y + D*x_inner) * silu(z) -> yb bf16 ----
  {
#pragma unroll
    for (int c2 = 0; c2 < 2; ++c2) {
      const int h = (wave * 2 + c2) * 16 + l16;
      const float dh = Dv[h];
#pragma unroll
      for (int rt = 0; rt < 2; ++rt)
#pragma unroll
        for (int r = 0; r < 4; ++r) {
          const int n = rt * 16 + q * 4 + r;
          const size_t grow = (size_t)(R0 + n) * HD + h;
          const float xv = b2f(xib[grow]);
          const float zv = b2f(zb[grow]);
          const float yv = acc[rt][c2][r] + dh * xv;
          const float sig = 1.f / (1.f + __expf(-zv));
          ((short*)yb)[n * 264 + h] = f2bs(yv * zv * sig);
        }
    }
  }
  __syncthreads();

  // ---- out GEMM: wave = 32 rows x 32 cols ----
  const int cw = wave * 32;
  f32x4 oacc[2][2] = {};
#pragma unroll
  for (int k = 0; k < HD; k += 32) {
    bf16x8 a0 = *(const bf16x8*)(yb + l16 * 264 + k + q * 8);
    bf16x8 a1 = *(const bf16x8*)(yb + (16 + l16) * 264 + k + q * 8);
#pragma unroll
    for (int t = 0; t < 2; ++t) {
      bf16x8 bfr = *(const bf16x8*)(wbout + (size_t)(cw + t * 16 + l16) * HD + k + q * 8);
      oacc[0][t] = __builtin_amdgcn_mfma_f32_16x16x32_bf16(a0, bfr, oacc[0][t], 0, 0, 0);
      oacc[1][t] = __builtin_amdgcn_mfma_f32_16x16x32_bf16(a1, bfr, oacc[1][t], 0, 0, 0);
    }
  }
  // pt = oacc + out_b + residual (pt region disjoint from yb)
#pragma unroll
  for (int t = 0; t < 2; ++t) {
    const int col = cw + t * 16 + l16;
    const float bias = out_b[col];
#pragma unroll
    for (int rt = 0; rt < 2; ++rt)
#pragma unroll
      for (int r = 0; r < 4; ++r) {
        const int row = rt * 16 + q * 4 + r;
        pt[row * PST + col] = oacc[rt][t][r] + bias + x[(size_t)(R0 + row) * HD + col];
      }
  }
  __syncthreads();

  // ---- LayerNorm: wave handles rows wave*4 .. wave*4+3 ----
#pragma unroll
  for (int rr = 0; rr < 4; ++rr) {
    const int row = wave * 4 + rr;
    float p = 0.f;
#pragma unroll
    for (int j = 0; j < 4; ++j) p += pt[row * PST + lane + 64 * j];
#pragma unroll
    for (int off = 32; off > 0; off >>= 1) p += __shfl_xor(p, off);
    const float mu = p * (1.f / 256.f);
    float v2 = 0.f;
#pragma unroll
    for (int j = 0; j < 4; ++j) {
      const float d = pt[row * PST + lane + 64 * j] - mu;
      v2 += d * d;
    }
#pragma unroll
    for (int off = 32; off > 0; off >>= 1) v2 += __shfl_xor(v2, off);
    const float rstd = rsqrtf(v2 * (1.f / 256.f) + LN_EPS);
    const size_t base = (size_t)(R0 + row) * HD;
#pragma unroll
    for (int j = 0; j < 4; ++j) {
      const int cc = lane + 64 * j;
      out[base + cc] = ln_g[cc] * (pt[row * PST + cc] - mu) * rstd + ln_b[cc];
    }
  }
}

// ---------------------------------------------------------------------------
extern "C" void kernel_launch(void* const* d_in, const int* in_sizes, int n_in,
                              void* d_out, int out_size, void* d_ws, size_t ws_size,
                              hipStream_t stream)
{
  const float* x     = (const float*)d_in[0];
  const float* in_w  = (const float*)d_in[1];
  const float* in_b  = (const float*)d_in[2];
  const float* xp_w  = (const float*)d_in[3];
  const float* xp_b  = (const float*)d_in[4];
  const float* dt_w  = (const float*)d_in[5];
  const float* dt_b  = (const float*)d_in[6];
  // d_in[7] = A_log — unused by the reference
  const float* Dv    = (const float*)d_in[8];
  const float* out_w = (const float*)d_in[9];
  const float* out_b = (const float*)d_in[10];
  const float* ln_g  = (const float*)d_in[11];
  const float* ln_b  = (const float*)d_in[12];

  char* ws = (char*)d_ws;
  bf16*  xib   = (bf16*)(ws);               // 8,388,608 B
  bf16*  zb    = (bf16*)(ws +  8388608);    // 8,388,608 B
  float* dbc   = (float*)(ws + 16777216);   // 2,162,688 B
  float* Mc    = (float*)(ws + 18939904);   // 8,388,608 B
  float* Gs    = (float*)(ws + 27328512);   //   524,288 B
  bf16*  wbin  = (bf16*)(ws + 27852800);    //   262,144 B
  bf16*  wbxp  = (bf16*)(ws + 28114944);    //    24,576 B
  bf16*  wbout = (bf16*)(ws + 28139520);    //   131,072 B
  float* out   = (float*)d_out;

  hipLaunchKernelGGL(k0_weights, dim3((NIW + NXP + NOW) / 1024), dim3(256),
                     0, stream, in_w, xp_w, out_w, wbin, wbxp, wbout);
  hipLaunchKernelGGL(k1_gemm, dim3(512), dim3(512), 0, stream,
                     x, wbin, in_b, xib, zb);
  hipLaunchKernelGGL(kS_xp_sum, dim3(BN / CHUNK), dim3(512), 0, stream,
                     xib, wbxp, xp_b, dt_w, dt_b, dbc, Mc);
  hipLaunchKernelGGL(k4a_prefix_local, dim3(NBATCH * NGRP * 4096 / 256),
                     dim3(256), 0, stream, Mc, Gs);
  hipLaunchKernelGGL(k4b_prefix_groups, dim3(NBATCH * 4096 / 256), dim3(256),
                     0, stream, Gs);
  hipLaunchKernelGGL(k56_scan_out_ln, dim3(BN / CHUNK), dim3(512), 0, stream,
                     xib, zb, dbc, dt_w, dt_b, Dv, Mc, Gs,
                     wbout, out_b, x, ln_g, ln_b, out);
}

// Round 12
// 139.117 us; speedup vs baseline: 1.0457x; 1.0457x over previous
//
#include <hip/hip_runtime.h>
#include <hip/hip_bf16.h>

// MambaBlock: H=256, S=16, B=2, N=8192. fp32 I/O.
// No decay (A_log unused) => pure prefix-sum SSM, chunk-parallel.
// Round 12: best-of hybrid -- R10's 256-thr k1 (64x64 wave tiles, 4:1
// MFMA:load) + 256-thr kS, R11's 512-thr k56 (8-way phase split, which
// measurably cut k56 from 52us to <43us).

#define HD 256
#define SD 16
#define NSEQ 8192
#define NBATCH 2
#define BN (NBATCH * NSEQ)      // 16384 rows
#define CHUNK 32
#define NCHUNK (NSEQ / CHUNK)   // 256
#define NGRP 16
#define GSZ (NCHUNK / NGRP)     // 16
#define LN_EPS 1e-5f
#define UST 40                  // bf16 row stride for Ut/Hst/Ctl
#define PST 257                 // f32 row stride for pt

#define NIW (2 * HD * HD)       // 131,072 in_w
#define NXP (48 * HD)           // 12,288  xp_w padded (src 33*256=8448)
#define NOW (HD * HD)           // 65,536  out_w

typedef __hip_bfloat16 bf16;
typedef __attribute__((ext_vector_type(8))) short bf16x8;
typedef __attribute__((ext_vector_type(4))) short short4v;
typedef __attribute__((ext_vector_type(4))) float f32x4;
typedef __attribute__((ext_vector_type(4))) unsigned int uint4v;

__device__ __forceinline__ float b2f(bf16 v) { return __bfloat162float(v); }
__device__ __forceinline__ short f2bs(float f) {
  union { bf16 b; short s; } u;
  u.b = __float2bfloat16(f);
  return u.s;
}
__device__ __forceinline__ unsigned int pack2(float a, float b) {
  return (unsigned int)(unsigned short)f2bs(a) |
         ((unsigned int)(unsigned short)f2bs(b) << 16);
}
__device__ __forceinline__ bf16x8 cvt_frag(const float* p) {
  bf16x8 r;
#pragma unroll
  for (int j = 0; j < 8; ++j) r[j] = f2bs(p[j]);
  return r;
}
__device__ __forceinline__ float softplus_f(float a) {
  return (a > 20.f) ? a : __logf(1.f + __expf(a));
}

// ---------------------------------------------------------------------------
// K0: weight conversions only.
// ---------------------------------------------------------------------------
__global__ __launch_bounds__(256) void k0_weights(
    const float* __restrict__ in_w, const float* __restrict__ xp_w,
    const float* __restrict__ out_w, bf16* __restrict__ wbin,
    bf16* __restrict__ wbxp, bf16* __restrict__ wbout)
{
  const int base = (blockIdx.x * 256 + threadIdx.x) * 4;
  if (base < NIW) {
    f32x4 v = *(const f32x4*)(in_w + base);
    *(short4v*)((short*)wbin + base) =
        short4v{f2bs(v[0]), f2bs(v[1]), f2bs(v[2]), f2bs(v[3])};
  } else if (base < NIW + NXP) {
    const int off = base - NIW;
    short4v s;
    if (off < 33 * HD) {
      f32x4 v = *(const f32x4*)(xp_w + off);
      s = short4v{f2bs(v[0]), f2bs(v[1]), f2bs(v[2]), f2bs(v[3])};
    } else {
      s = short4v{0, 0, 0, 0};
    }
    *(short4v*)((short*)wbxp + off) = s;
  } else if (base < NIW + NXP + NOW) {
    const int off = base - NIW - NXP;
    f32x4 v = *(const f32x4*)(out_w + off);
    *(short4v*)((short*)wbout + off) =
        short4v{f2bs(v[0]), f2bs(v[1]), f2bs(v[2]), f2bs(v[3])};
  }
}

// ---------------------------------------------------------------------------
// K1 (256 thr): tiled GEMM [x_inner|z] = x @ in_w^T + in_b (bf16 out).
// Wave = 64x64 quadrant (16 MFMA : 4 LDS + 4 global loads). A staged
// fp32->bf16 in LDS (aliased with epilogue Ct). rt = bid&127 XCD-local.
// ---------------------------------------------------------------------------
__global__ __launch_bounds__(256) void k1_gemm(
    const float* __restrict__ x, const bf16* __restrict__ wbin,
    const float* __restrict__ in_b, bf16* __restrict__ xib,
    bf16* __restrict__ zb)
{
  __shared__ __align__(16) char smem[128 * 264 * 2];   // 67,584 B
  bf16* At = (bf16*)smem;        // [128][264] bf16 A-tile
  float* Ct = (float*)smem;      // [128][132] f32, aliased after GEMM

  const int tid = threadIdx.x;
  const int rt = blockIdx.x & 127, ct = blockIdx.x >> 7;
  const int R0 = rt * 128, C0 = ct * 128;
  const int wave = tid >> 6, lane = tid & 63, q = lane >> 4, l16 = lane & 15;

  // stage A: 128 rows x 256 k, fp32 -> bf16, coalesced
#pragma unroll
  for (int it = 0; it < 16; ++it) {
    const int f = tid + it * 256;
    const int row = f >> 5, g = f & 31;
    bf16x8 v = cvt_frag(x + (size_t)(R0 + row) * HD + g * 8);
    *(bf16x8*)(At + row * 264 + g * 8) = v;
  }
  __syncthreads();

  // GEMM: wave = 64x64 quadrant; A from LDS, B from global
  const int rowHalf = (wave & 1) * 64;
  const int colHalf = (wave >> 1) * 64;
  f32x4 acc[4][4] = {};
  const bf16* bp = wbin + (size_t)(C0 + colHalf + l16) * HD + q * 8;
#pragma unroll
  for (int k = 0; k < HD; k += 32) {
    bf16x8 a[4], b[4];
#pragma unroll
    for (int i = 0; i < 4; ++i)
      a[i] = *(const bf16x8*)(At + (rowHalf + i * 16 + l16) * 264 + k + q * 8);
#pragma unroll
    for (int j = 0; j < 4; ++j)
      b[j] = *(const bf16x8*)(bp + (size_t)j * 16 * HD + k);
#pragma unroll
    for (int i = 0; i < 4; ++i)
#pragma unroll
      for (int j = 0; j < 4; ++j)
        acc[i][j] = __builtin_amdgcn_mfma_f32_16x16x32_bf16(a[i], b[j], acc[i][j], 0, 0, 0);
  }
  __syncthreads();   // At reads complete before Ct overwrite

#pragma unroll
  for (int j = 0; j < 4; ++j) {
    const int col = colHalf + j * 16 + l16;
    const float bias = in_b[C0 + col];
#pragma unroll
    for (int i = 0; i < 4; ++i)
#pragma unroll
      for (int r = 0; r < 4; ++r)
        Ct[(rowHalf + i * 16 + q * 4 + r) * 132 + col] = acc[i][j][r] + bias;
  }
  __syncthreads();

  bf16* dst = (C0 < HD) ? xib : zb;
  const int Cd = (C0 < HD) ? C0 : (C0 - HD);
#pragma unroll
  for (int it = 0; it < 8; ++it) {
    const int f = tid + it * 256;
    const int row = f >> 4, g = f & 15;
    bf16x8 v = cvt_frag(Ct + row * 132 + g * 8);
    *(bf16x8*)(dst + (size_t)(R0 + row) * HD + Cd + g * 8) = v;
  }
}

// ---------------------------------------------------------------------------
// KS (256 thr): per 32-row chunk: xp-GEMM -> dbc; u -> Ut[h][n];
// Mc = B^T @ U via MFMA ([s][h] layout).
// ---------------------------------------------------------------------------
__global__ __launch_bounds__(256) void kS_xp_sum(
    const bf16* __restrict__ xib, const bf16* __restrict__ wbxp,
    const float* __restrict__ xp_b, const float* __restrict__ dt_w,
    const float* __restrict__ dt_b, float* __restrict__ dbc,
    float* __restrict__ Mc)
{
  __shared__ __align__(16) bf16 xt[32 * 264];    // 16.9 KB
  __shared__ __align__(16) bf16 wp[48 * 264];    // 25.3 KB
  __shared__ __align__(16) float sdbc[32][33];   // 4.2 KB
  __shared__ __align__(16) bf16 sBt[16 * UST];   // 1.25 KB
  __shared__ __align__(16) bf16 Ut[256 * UST];   // 20 KB
  const int tid = threadIdx.x;
  const int wave = tid >> 6, lane = tid & 63, q = lane >> 4, l16 = lane & 15;
  const int cix = blockIdx.x;
  const int R0 = cix * CHUNK;

#pragma unroll
  for (int it = 0; it < 4; ++it) {
    const int f = tid + it * 256, row = f >> 5, g = f & 31;
    *(bf16x8*)(xt + row * 264 + g * 8) =
        *(const bf16x8*)(xib + (size_t)(R0 + row) * HD + g * 8);
  }
#pragma unroll
  for (int it = 0; it < 6; ++it) {
    const int f = tid + it * 256, row = f >> 5, g = f & 31;
    *(bf16x8*)(wp + row * 264 + g * 8) =
        *(const bf16x8*)(wbxp + (size_t)row * HD + g * 8);
  }
  __syncthreads();

  if (wave < 2) {
    f32x4 pacc[3] = {};
#pragma unroll
    for (int k = 0; k < HD; k += 32) {
      bf16x8 af = *(const bf16x8*)(xt + (wave * 16 + l16) * 264 + k + q * 8);
#pragma unroll
      for (int t = 0; t < 3; ++t) {
        bf16x8 bfr = *(const bf16x8*)(wp + (t * 16 + l16) * 264 + k + q * 8);
        pacc[t] = __builtin_amdgcn_mfma_f32_16x16x32_bf16(af, bfr, pacc[t], 0, 0, 0);
      }
    }
#pragma unroll
    for (int t = 0; t < 3; ++t) {
      const int col = t * 16 + l16;
      if (col < 33) {
        const float bias = xp_b[col];
#pragma unroll
        for (int r = 0; r < 4; ++r) {
          const int row = wave * 16 + q * 4 + r;
          const float v = pacc[t][r] + bias;
          sdbc[row][col] = v;
          if (col >= 1 && col < 17)
            *((short*)sBt + (col - 1) * UST + row) = f2bs(v);
        }
      }
    }
  }
  __syncthreads();

  // dbc flat copy out
  {
    const float* sflat = &sdbc[0][0];
    for (int idx = tid; idx < CHUNK * 33; idx += 256)
      dbc[(size_t)R0 * 33 + idx] = sflat[idx];
  }
  // u -> Ut[h][n]
  {
    const int h = tid;
    const float dtw = dt_w[h], dtb = dt_b[h];
    unsigned int up[16];
#pragma unroll
    for (int n2 = 0; n2 < 16; ++n2) {
      const int n = 2 * n2;
      const float xv0 = b2f(xt[n * 264 + h]);
      const float xv1 = b2f(xt[(n + 1) * 264 + h]);
      const float u0 = xv0 * softplus_f(sdbc[n][0] * dtw + dtb);
      const float u1 = xv1 * softplus_f(sdbc[n + 1][0] * dtw + dtb);
      up[n2] = pack2(u0, u1);
    }
    uint4v* dst = (uint4v*)(Ut + h * UST);
#pragma unroll
    for (int j = 0; j < 4; ++j)
      dst[j] = uint4v{up[4 * j], up[4 * j + 1], up[4 * j + 2], up[4 * j + 3]};
  }
  __syncthreads();

  // Mc = B^T @ U : wave w -> col-tiles w*4..w*4+3
  {
    bf16x8 af = *(const bf16x8*)(sBt + l16 * UST + q * 8);
    f32x4 macc[4] = {};
#pragma unroll
    for (int c4 = 0; c4 < 4; ++c4) {
      const int ct = wave * 4 + c4;
      bf16x8 bu = *(const bf16x8*)(Ut + (ct * 16 + l16) * UST + q * 8);
      macc[c4] = __builtin_amdgcn_mfma_f32_16x16x32_bf16(af, bu, macc[c4], 0, 0, 0);
    }
    float* mbase = Mc + (size_t)cix * 4096;
#pragma unroll
    for (int c4 = 0; c4 < 4; ++c4) {
      const int h = (wave * 4 + c4) * 16 + l16;
#pragma unroll
      for (int r = 0; r < 4; ++r)
        mbase[(q * 4 + r) * HD + h] = macc[c4][r];   // [s][h]
    }
  }
}

// ---------------------------------------------------------------------------
// K4a: exclusive prefix of Mc within each group of GSZ chunks; totals -> Gs.
// ---------------------------------------------------------------------------
__global__ __launch_bounds__(256) void k4a_prefix_local(
    float* __restrict__ Mc, float* __restrict__ Gs)
{
  const int tid = blockIdx.x * 256 + threadIdx.x;   // 131072
  const int b = tid >> 16;
  const int g = (tid >> 12) & (NGRP - 1);
  const int hs = tid & 4095;
  float run = 0.f;
#pragma unroll
  for (int i = 0; i < GSZ; ++i) {
    const size_t idx = ((size_t)(b * NCHUNK + g * GSZ + i)) * 4096 + hs;
    const float v = Mc[idx];
    Mc[idx] = run;
    run += v;
  }
  Gs[((size_t)(b * NGRP + g)) * 4096 + hs] = run;
}

// ---------------------------------------------------------------------------
// K4b: exclusive prefix over the NGRP group totals (in-place).
// ---------------------------------------------------------------------------
__global__ __launch_bounds__(256) void k4b_prefix_groups(float* __restrict__ Gs)
{
  const int tid = blockIdx.x * 256 + threadIdx.x;   // 8192
  const int b = tid >> 12;
  const int hs = tid & 4095;
  float run = 0.f;
#pragma unroll
  for (int g = 0; g < NGRP; ++g) {
    const size_t idx = ((size_t)(b * NGRP + g)) * 4096 + hs;
    const float v = Gs[idx];
    Gs[idx] = run;
    run += v;
  }
}

// ---------------------------------------------------------------------------
// K56 (512 thr / 8 waves): Hst prefetch hoisted; T/Ctl/u built 512-wide;
// y = T@U + C@Hseed (8 waves x 2 col-tiles); gate in regs -> yb bf16;
// out-GEMM 32 cols/wave; residual + LN (4 rows/wave).
// ---------------------------------------------------------------------------
__global__ __launch_bounds__(512) void k56_scan_out_ln(
    const bf16* __restrict__ xib, const bf16* __restrict__ zb,
    const float* __restrict__ dbc, const float* __restrict__ dt_w,
    const float* __restrict__ dt_b, const float* __restrict__ Dv,
    const float* __restrict__ Mc, const float* __restrict__ Gs,
    const bf16* __restrict__ wbout, const float* __restrict__ out_b,
    const float* __restrict__ x, const float* __restrict__ ln_g,
    const float* __restrict__ ln_b, float* __restrict__ out)
{
  __shared__ __align__(16) char un[53376];
  bf16* Ut  = (bf16*)un;                 // [256][UST]  20,480 B
  bf16* Hst = (bf16*)(un + 20480);       // [256][UST]  20,480 B
  bf16* Ctl = (bf16*)(un + 40960);       // [32][UST]    2,560 B
  bf16* Tt  = (bf16*)(un + 43520);       // [32][32]     2,048 B
  bf16* yb  = (bf16*)un;                 // phase3: [32][264] 16,896 B
  float* pt = (float*)(un + 20480);      // phase4: [32][PST] 32,896 B
  __shared__ float sdbc[32][33];

  const int tid = threadIdx.x;
  const int wave = tid >> 6, lane = tid & 63, q = lane >> 4, l16 = lane & 15;
  const int cix = blockIdx.x;
  const int R0 = cix * CHUNK;
  const int b = cix >> 8;
  const int cchunk = cix & 255;

  // ---- Hst prefetch (independent of sdbc -> overlaps its load) ----
  {
    const int h = tid & 255;
    const int sh = tid >> 8;
    const float* mp = Mc + (size_t)cix * 4096 + sh * 8 * HD + h;
    const float* gp = Gs + ((size_t)(b * NGRP + cchunk / GSZ)) * 4096 + sh * 8 * HD + h;
    unsigned int hp[4];
#pragma unroll
    for (int s2 = 0; s2 < 4; ++s2) {
      const int s = 2 * s2;
      hp[s2] = pack2(mp[s * HD] + gp[s * HD], mp[(s + 1) * HD] + gp[(s + 1) * HD]);
    }
    uint4v* hd = (uint4v*)(Hst + h * UST);
    hd[sh] = uint4v{hp[0], hp[1], hp[2], hp[3]};
    hd[2 + sh] = uint4v{0, 0, 0, 0};
  }
  // ---- sdbc load (flat coalesced) ----
  {
    float* sflat = &sdbc[0][0];
    for (int idx = tid; idx < CHUNK * 33; idx += 512)
      sflat[idx] = dbc[(size_t)R0 * 33 + idx];
  }
  __syncthreads();

  // ---- T = (C @ B^T) masked (m <= n): thread = (n, m-pair) ----
  {
    const int n = tid >> 4;
    const int m0 = (tid & 15) * 2;
    float cn[SD];
#pragma unroll
    for (int s = 0; s < SD; ++s) cn[s] = sdbc[n][17 + s];
    float t0 = 0.f, t1 = 0.f;
#pragma unroll
    for (int s = 0; s < SD; ++s) {
      t0 += cn[s] * sdbc[m0][1 + s];
      t1 += cn[s] * sdbc[m0 + 1][1 + s];
    }
    *(unsigned int*)((short*)Tt + n * 32 + m0) =
        pack2((m0 <= n) ? t0 : 0.f, (m0 + 1 <= n) ? t1 : 0.f);
  }
  // ---- Ctl[n][k] = C (k<16) else 0: thread = (n, k-pair) ----
  {
    const int n = tid >> 4, k0 = (tid & 15) * 2;
    const float v0 = (k0 < SD) ? sdbc[n][17 + k0] : 0.f;
    const float v1 = (k0 + 1 < SD) ? sdbc[n][17 + k0 + 1] : 0.f;
    *(unsigned int*)((short*)Ctl + n * UST + k0) = pack2(v0, v1);
  }
  // ---- u -> Ut[h][n], split (h, n-half) ----
  {
    const int h = tid & 255;
    const int sh = tid >> 8;
    const float dtw = dt_w[h], dtb = dt_b[h];
    unsigned int up[8];
#pragma unroll
    for (int n2 = 0; n2 < 8; ++n2) {
      const int n = sh * 16 + 2 * n2;
      const float xv0 = b2f(xib[(size_t)(R0 + n) * HD + h]);
      const float xv1 = b2f(xib[(size_t)(R0 + n + 1) * HD + h]);
      const float u0 = xv0 * softplus_f(sdbc[n][0] * dtw + dtb);
      const float u1 = xv1 * softplus_f(sdbc[n + 1][0] * dtw + dtb);
      up[n2] = pack2(u0, u1);
    }
    uint4v* dst = (uint4v*)(Ut + h * UST + sh * 16);
    dst[0] = uint4v{up[0], up[1], up[2], up[3]};
    dst[1] = uint4v{up[4], up[5], up[6], up[7]};
  }
  __syncthreads();

  // ---- y MFMAs: 8 waves x 2 col-tiles, 2 row-tiles ----
  f32x4 acc[2][2] = {};
  {
    bf16x8 aT0 = *(const bf16x8*)(Tt + l16 * 32 + q * 8);
    bf16x8 aT1 = *(const bf16x8*)(Tt + (16 + l16) * 32 + q * 8);
    bf16x8 aC0 = *(const bf16x8*)(Ctl + l16 * UST + q * 8);
    bf16x8 aC1 = *(const bf16x8*)(Ctl + (16 + l16) * UST + q * 8);
#pragma unroll
    for (int c2 = 0; c2 < 2; ++c2) {
      const int ct = wave * 2 + c2;
      bf16x8 bu = *(const bf16x8*)(Ut + (ct * 16 + l16) * UST + q * 8);
      bf16x8 bh = *(const bf16x8*)(Hst + (ct * 16 + l16) * UST + q * 8);
      acc[0][c2] = __builtin_amdgcn_mfma_f32_16x16x32_bf16(aT0, bu, acc[0][c2], 0, 0, 0);
      acc[0][c2] = __builtin_amdgcn_mfma_f32_16x16x32_bf16(aC0, bh, acc[0][c2], 0, 0, 0);
      acc[1][c2] = __builtin_amdgcn_mfma_f32_16x16x32_bf16(aT1, bu, acc[1][c2], 0, 0, 0);
      acc[1][c2] = __builtin_amdgcn_mfma_f32_16x16x32_bf16(aC1, bh, acc[1][c2], 0, 0, 0);
    }
  }
  __syncthreads();   // operand tiles dead; union becomes yb/pt

  // ---- gate in registers: y = (y + D*x_inner) * silu(z) -> yb bf16 ----
  {
#pragma unroll
    for (int c2 = 0; c2 < 2; ++c2) {
      const int h = (wave * 2 + c2) * 16 + l16;
      const float dh = Dv[h];
#pragma unroll
      for (int rt = 0; rt < 2; ++rt)
#pragma unroll
        for (int r = 0; r < 4; ++r) {
          const int n = rt * 16 + q * 4 + r;
          const size_t grow = (size_t)(R0 + n) * HD + h;
          const float xv = b2f(xib[grow]);
          const float zv = b2f(zb[grow]);
          const float yv = acc[rt][c2][r] + dh * xv;
          const float sig = 1.f / (1.f + __expf(-zv));
          ((short*)yb)[n * 264 + h] = f2bs(yv * zv * sig);
        }
    }
  }
  __syncthreads();

  // ---- out GEMM: wave = 32 rows x 32 cols ----
  const int cw = wave * 32;
  f32x4 oacc[2][2] = {};
#pragma unroll
  for (int k = 0; k < HD; k += 32) {
    bf16x8 a0 = *(const bf16x8*)(yb + l16 * 264 + k + q * 8);
    bf16x8 a1 = *(const bf16x8*)(yb + (16 + l16) * 264 + k + q * 8);
#pragma unroll
    for (int t = 0; t < 2; ++t) {
      bf16x8 bfr = *(const bf16x8*)(wbout + (size_t)(cw + t * 16 + l16) * HD + k + q * 8);
      oacc[0][t] = __builtin_amdgcn_mfma_f32_16x16x32_bf16(a0, bfr, oacc[0][t], 0, 0, 0);
      oacc[1][t] = __builtin_amdgcn_mfma_f32_16x16x32_bf16(a1, bfr, oacc[1][t], 0, 0, 0);
    }
  }
  // pt = oacc + out_b + residual (pt region disjoint from yb)
#pragma unroll
  for (int t = 0; t < 2; ++t) {
    const int col = cw + t * 16 + l16;
    const float bias = out_b[col];
#pragma unroll
    for (int rt = 0; rt < 2; ++rt)
#pragma unroll
      for (int r = 0; r < 4; ++r) {
        const int row = rt * 16 + q * 4 + r;
        pt[row * PST + col] = oacc[rt][t][r] + bias + x[(size_t)(R0 + row) * HD + col];
      }
  }
  __syncthreads();

  // ---- LayerNorm: wave handles rows wave*4 .. wave*4+3 ----
#pragma unroll
  for (int rr = 0; rr < 4; ++rr) {
    const int row = wave * 4 + rr;
    float p = 0.f;
#pragma unroll
    for (int j = 0; j < 4; ++j) p += pt[row * PST + lane + 64 * j];
#pragma unroll
    for (int off = 32; off > 0; off >>= 1) p += __shfl_xor(p, off);
    const float mu = p * (1.f / 256.f);
    float v2 = 0.f;
#pragma unroll
    for (int j = 0; j < 4; ++j) {
      const float d = pt[row * PST + lane + 64 * j] - mu;
      v2 += d * d;
    }
#pragma unroll
    for (int off = 32; off > 0; off >>= 1) v2 += __shfl_xor(v2, off);
    const float rstd = rsqrtf(v2 * (1.f / 256.f) + LN_EPS);
    const size_t base = (size_t)(R0 + row) * HD;
#pragma unroll
    for (int j = 0; j < 4; ++j) {
      const int cc = lane + 64 * j;
      out[base + cc] = ln_g[cc] * (pt[row * PST + cc] - mu) * rstd + ln_b[cc];
    }
  }
}

// ---------------------------------------------------------------------------
extern "C" void kernel_launch(void* const* d_in, const int* in_sizes, int n_in,
                              void* d_out, int out_size, void* d_ws, size_t ws_size,
                              hipStream_t stream)
{
  const float* x     = (const float*)d_in[0];
  const float* in_w  = (const float*)d_in[1];
  const float* in_b  = (const float*)d_in[2];
  const float* xp_w  = (const float*)d_in[3];
  const float* xp_b  = (const float*)d_in[4];
  const float* dt_w  = (const float*)d_in[5];
  const float* dt_b  = (const float*)d_in[6];
  // d_in[7] = A_log — unused by the reference
  const float* Dv    = (const float*)d_in[8];
  const float* out_w = (const float*)d_in[9];
  const float* out_b = (const float*)d_in[10];
  const float* ln_g  = (const float*)d_in[11];
  const float* ln_b  = (const float*)d_in[12];

  char* ws = (char*)d_ws;
  bf16*  xib   = (bf16*)(ws);               // 8,388,608 B
  bf16*  zb    = (bf16*)(ws +  8388608);    // 8,388,608 B
  float* dbc   = (float*)(ws + 16777216);   // 2,162,688 B
  float* Mc    = (float*)(ws + 18939904);   // 8,388,608 B
  float* Gs    = (float*)(ws + 27328512);   //   524,288 B
  bf16*  wbin  = (bf16*)(ws + 27852800);    //   262,144 B
  bf16*  wbxp  = (bf16*)(ws + 28114944);    //    24,576 B
  bf16*  wbout = (bf16*)(ws + 28139520);    //   131,072 B
  float* out   = (float*)d_out;

  hipLaunchKernelGGL(k0_weights, dim3((NIW + NXP + NOW) / 1024), dim3(256),
                     0, stream, in_w, xp_w, out_w, wbin, wbxp, wbout);
  hipLaunchKernelGGL(k1_gemm, dim3(512), dim3(256), 0, stream,
                     x, wbin, in_b, xib, zb);
  hipLaunchKernelGGL(kS_xp_sum, dim3(BN / CHUNK), dim3(256), 0, stream,
                     xib, wbxp, xp_b, dt_w, dt_b, dbc, Mc);
  hipLaunchKernelGGL(k4a_prefix_local, dim3(NBATCH * NGRP * 4096 / 256),
                     dim3(256), 0, stream, Mc, Gs);
  hipLaunchKernelGGL(k4b_prefix_groups, dim3(NBATCH * 4096 / 256), dim3(256),
                     0, stream, Gs);
  hipLaunchKernelGGL(k56_scan_out_ln, dim3(BN / CHUNK), dim3(512), 0, stream,
                     xib, zb, dbc, dt_w, dt_b, Dv, Mc, Gs,
                     wbout, out_b, x, ln_g, ln_b, out);
}